// Round 12
// baseline (75.367 us; speedup 1.0000x reference)
//
#include <hip/hip_runtime.h>
#include <hip/hip_bf16.h>
#include <math.h>

#define BB 8
#define TT 4096
#define HD 64

typedef __attribute__((ext_vector_type(8))) short short8;
typedef __attribute__((ext_vector_type(4))) float f32x4;
typedef __attribute__((ext_vector_type(16))) float f32x16;
typedef __attribute__((ext_vector_type(2))) unsigned int uint2v;
typedef __attribute__((ext_vector_type(4))) unsigned int uint4v;

#define LOG2E 1.44269504088896f

// 1-inst packed f32->bf16 (RNE). src0 -> lo, src1 -> hi (matches a | b<<16).
__device__ __forceinline__ unsigned pack_bf2(float a, float b) {
    unsigned r;
    asm("v_cvt_pk_bf16_f32 %0, %1, %2" : "=v"(r) : "v"(a), "v"(b));
    return r;
}
__device__ __forceinline__ unsigned short bfbits(float f) {
    unsigned r;
    asm("v_cvt_pk_bf16_f32 %0, %1, %2" : "=v"(r) : "v"(f), "v"(f));
    return (unsigned short)r;
}
__device__ __forceinline__ float bf2f(unsigned short u) {
    unsigned v = (unsigned)u << 16;
    return __builtin_bit_cast(float, v);
}
__device__ __forceinline__ float fexp2(float x) {     // raw v_exp_f32
    return __builtin_amdgcn_exp2f(x);
}
__device__ __forceinline__ short8 cvt8(float4 a, float4 b, float sc) {
    uint4v u;
    u[0] = pack_bf2(a.x * sc, a.y * sc);
    u[1] = pack_bf2(a.z * sc, a.w * sc);
    u[2] = pack_bf2(b.x * sc, b.y * sc);
    u[3] = pack_bf2(b.z * sc, b.w * sc);
    return __builtin_bit_cast(short8, u);
}

// ---------------- Kernel 1: MFMA QKV projection (unchanged, proven) ----------------
__global__ __launch_bounds__(256) void qkv_proj_mfma(
    const float* __restrict__ x,
    const float* __restrict__ Wk, const float* __restrict__ Wq, const float* __restrict__ Wv,
    unsigned short* __restrict__ qo, unsigned short* __restrict__ ko,
    unsigned short* __restrict__ vto)
{
    __shared__ short lds[20480];
    short* xls = lds;
    short* wls = lds + 8192;

    const int tid = threadIdx.x;
    const int l = tid & 63, w = tid >> 6;
    const int hi = l >> 5, c31 = l & 31;
    const long t0 = (long)blockIdx.x * 128;
    const int b = (int)(t0 >> 12);
    const int tl0 = (int)(t0 & 4095);

#pragma unroll
    for (int i = 0; i < 4; ++i) {
        int slot = tid + 256 * i;
        int row = slot >> 3, bl = slot & 7;
        const float* xp = x + (t0 + row) * 64 + 8 * bl;
        float4 a = *(const float4*)xp;
        float4 bq = *(const float4*)(xp + 4);
        *(short8*)&xls[row * 64 + 8 * (bl ^ (row & 7))] = cvt8(a, bq, 1.f);
    }
#pragma unroll
    for (int i = 0; i < 6; ++i) {
        int slot = tid + 256 * i;
        int row = slot >> 3, bl = slot & 7;
        const float* wp;
        float sc;
        if (row < 64)       { wp = Wq + row * 64;         sc = 0.125f * LOG2E; }
        else if (row < 128) { wp = Wk + (row - 64) * 64;  sc = 1.f; }
        else                { wp = Wv + (row - 128) * 64; sc = 1.f; }
        wp += 8 * bl;
        float4 a = *(const float4*)wp;
        float4 bq = *(const float4*)(wp + 4);
        *(short8*)&wls[row * 64 + 8 * (bl ^ (row & 7))] = cvt8(a, bq, sc);
    }
    __syncthreads();

    short8 xf[4];
#pragma unroll
    for (int ki = 0; ki < 4; ++ki) {
        int row = 32 * w + c31;
        xf[ki] = *(const short8*)&xls[row * 64 + 8 * ((2 * ki + hi) ^ (row & 7))];
    }
    f32x16 cqk[4] = {};
#pragma unroll
    for (int nt = 0; nt < 4; ++nt) {
#pragma unroll
        for (int ki = 0; ki < 4; ++ki) {
            int row = 32 * nt + c31;
            short8 wf = *(const short8*)&wls[row * 64 + 8 * ((2 * ki + hi) ^ (row & 7))];
            cqk[nt] = __builtin_amdgcn_mfma_f32_32x32x16_bf16(xf[ki], wf, cqk[nt], 0, 0, 0);
        }
    }
    f32x16 cv[2] = {};
#pragma unroll
    for (int rt = 0; rt < 2; ++rt) {
#pragma unroll
        for (int ki = 0; ki < 4; ++ki) {
            int row = 128 + 32 * rt + c31;
            short8 wf = *(const short8*)&wls[row * 64 + 8 * ((2 * ki + hi) ^ (row & 7))];
            cv[rt] = __builtin_amdgcn_mfma_f32_32x32x16_bf16(wf, xf[ki], cv[rt], 0, 0, 0);
        }
    }
#pragma unroll
    for (int rt = 0; rt < 2; ++rt) {
#pragma unroll
        for (int r = 0; r < 16; ++r) {
            int h = 32 * rt + (r & 3) + 8 * (r >> 2) + 4 * hi;
            vto[((long)b * 64 + h) * 4096 + tl0 + 32 * w + c31] = bfbits(cv[rt][r]);
        }
    }

    __syncthreads();
    short* cb = lds;
#pragma unroll
    for (int nt = 0; nt < 4; ++nt) {
#pragma unroll
        for (int r = 0; r < 16; ++r) {
            int trow = 32 * w + (r & 3) + 8 * (r >> 2) + 4 * hi;
            cb[trow * 136 + 32 * nt + c31] = (short)bfbits(cqk[nt][r]);
        }
    }
    __syncthreads();
    {
        int row = tid >> 1, seg = tid & 1;
        const short8* cp = (const short8*)&cb[row * 136 + seg * 64];
        unsigned short* dst = (seg == 0 ? qo : ko) + (t0 + row) * 64;
#pragma unroll
        for (int i = 0; i < 8; ++i) ((short8*)dst)[i] = cp[i];
    }
}

// ---------------- Kernel 2: MFMA flash attention, dual-strip waves ----------------
// 128 thr = 2 waves; each wave owns 64 q-rows as TWO independent 32-row strips
// (A: +0..31, B: +32..63) -> 2 ILP chains/wave, K/V ds_reads shared by both.
// Shell identical to round 11: grid 640, chunk 16, 3-buffer counted-vmcnt,
// partial/combine layout unchanged. Strips share diag tile lastg = 2qt+w:
// A masks kt=0 (kt=1 fully masked, skipped); B masks kt=1 (kt=0 free).
__global__ __launch_bounds__(128, 2) void attn_mfma(
    const unsigned short* __restrict__ qg,
    const unsigned short* __restrict__ kg,
    const unsigned short* __restrict__ vtg,
    unsigned short* __restrict__ Opart,
    float2* __restrict__ ml,
    float* __restrict__ outg)
{
    __shared__ short kls[3][4096];
    __shared__ short vls[3][4096];

    const int tid = threadIdx.x;
    const int l = tid & 63, w = tid >> 6;     // w in {0,1}
    const int q = l & 31, hi = l >> 5;
    const int qs7 = q & 7;

    const int bid = blockIdx.x;
    const int b = bid & 7;
    const int j = bid >> 3;
    int qt = 0, ci = 0;
    {
        int acc = 0;
        for (int qq = 31; qq >= 0; --qq) {       // descending size (LPT)
            int nc = (2 * qq + 17) >> 4;
            if (j < acc + nc) { qt = qq; ci = j - acc; break; }
            acc += nc;
        }
    }
    const int nch = (2 * qt + 17) >> 4;
    int ntile = 2 * qt + 2 - 16 * ci;
    if (ntile > 16) ntile = 16;
    const int c0 = ci * 1024;

    const int q0b = qt * 128;
    const int rA = q0b + 64 * w + q;           // strip A row
    const int rB = rA + 32;                    // strip B row
    const int lastg = 2 * qt + w;              // shared diagonal KV tile

    const unsigned short* qbase = qg + (long)b * TT * HD;
    short8 qfA[4], qfB[4];
#pragma unroll
    for (int ki = 0; ki < 4; ++ki) {
        qfA[ki] = *(const short8*)(qbase + (long)rA * HD + 16 * ki + 8 * hi);
        qfB[ki] = *(const short8*)(qbase + (long)rB * HD + 16 * ki + 8 * hi);
    }

    // hoisted LDS fragment byte offsets (same for K and V^T reads)
    int ofs[2][4];
#pragma unroll
    for (int a = 0; a < 2; ++a)
#pragma unroll
        for (int i2 = 0; i2 < 4; ++i2)
            ofs[a][i2] = (32 * a + q) * 128 + 16 * ((2 * i2 + hi) ^ qs7);

    f32x16 oA[2] = {}, oB[2] = {};
    float mA = -INFINITY, lsA = 0.f;           // per-half partials (epilogue shfl)
    float mB = -INFINITY, lsB = 0.f;

    const unsigned short* kbase = kg + (long)b * TT * HD;
    const unsigned short* vbase = vtg + (long)b * HD * TT;

    // staging: 128 thr x 4 chunks of 16 rows. row = 16c + 8w + r8, bl pre-swizzled.
    const int r8 = l >> 3;
    const int blsw = (l & 7) ^ r8;
    const long koff0 = (long)(8 * w + r8) * HD + 8 * blsw;
    const long voff0 = (long)(8 * w + r8) * TT + 8 * blsw;

#define STAGE(buf_, s_) do {                                                            \
    _Pragma("unroll")                                                                   \
    for (int c_ = 0; c_ < 4; ++c_) {                                                    \
        const unsigned short* kp_ = kbase + (long)((s_) + 16 * c_) * HD + koff0;        \
        const unsigned short* vp_ = vbase + (long)(16 * c_) * TT + voff0 + (s_);        \
        short* kd_ = &kls[buf_][1024 * c_ + 512 * w];                                   \
        short* vd_ = &vls[buf_][1024 * c_ + 512 * w];                                   \
        __builtin_amdgcn_global_load_lds((const __attribute__((address_space(1))) void*)kp_, \
                                         (__attribute__((address_space(3))) void*)kd_, 16, 0, 0); \
        __builtin_amdgcn_global_load_lds((const __attribute__((address_space(1))) void*)vp_, \
                                         (__attribute__((address_space(3))) void*)vd_, 16, 0, 0); \
    }                                                                                   \
} while (0)

    STAGE(0, c0);
    if (ntile > 1) STAGE(1, c0 + 64);

    int cur = 0, nxt2 = 2;
    for (int it = 0; it < ntile; ++it) {
        const int s0 = c0 + (it << 6);
        if (it + 1 < ntile) asm volatile("s_waitcnt vmcnt(8)" ::: "memory");
        else                asm volatile("s_waitcnt vmcnt(0)" ::: "memory");
        __builtin_amdgcn_s_barrier();
        __builtin_amdgcn_sched_barrier(0);
        if (it + 2 < ntile) STAGE(nxt2, s0 + 128);

        const int gti = ci * 16 + it;
        if (gti <= lastg) {
            const bool dg = (gti == lastg);
            const int nktA = dg ? 1 : 2;       // A: diag upper kt fully masked
            const short* kb_ = kls[cur];
            const short* vb_ = vls[cur];

            // ---- shared K fragments ----
            short8 kf[8];
#pragma unroll
            for (int a = 0; a < 2; ++a)
#pragma unroll
                for (int i2 = 0; i2 < 4; ++i2)
                    kf[4 * a + i2] = *(const short8*)((const char*)kb_ + ofs[a][i2]);

            // ---- S^T = K Q^T, both strips (independent chains) ----
            f32x16 sA[2] = {}, sB[2] = {};
            __builtin_amdgcn_s_setprio(1);
#pragma unroll
            for (int ki = 0; ki < 4; ++ki) {
                sA[0] = __builtin_amdgcn_mfma_f32_32x32x16_bf16(kf[ki], qfA[ki], sA[0], 0, 0, 0);
                sB[0] = __builtin_amdgcn_mfma_f32_32x32x16_bf16(kf[ki], qfB[ki], sB[0], 0, 0, 0);
            }
#pragma unroll
            for (int ki = 0; ki < 4; ++ki) {
                if (nktA == 2)
                    sA[1] = __builtin_amdgcn_mfma_f32_32x32x16_bf16(kf[4 + ki], qfA[ki], sA[1], 0, 0, 0);
                sB[1] = __builtin_amdgcn_mfma_f32_32x32x16_bf16(kf[4 + ki], qfB[ki], sB[1], 0, 0, 0);
            }
            __builtin_amdgcn_s_setprio(0);

            // ---- causal masks (diag tile only; strip-specific kt) ----
            if (dg) {
#pragma unroll
                for (int r = 0; r < 16; ++r) {
                    int kkg0 = s0 + (r & 3) + 8 * (r >> 2) + 4 * hi;
                    if (kkg0 > rA) sA[0][r] = -INFINITY;
                    if (kkg0 + 32 > rB) sB[1][r] = -INFINITY;
                }
            }

            // ---- strip A softmax ----
            {
                float t8[8];
#pragma unroll
                for (int r = 0; r < 8; ++r) {
                    float a = fmaxf(sA[0][r], sA[0][r + 8]);
                    if (nktA == 2) a = fmaxf(a, fmaxf(sA[1][r], sA[1][r + 8]));
                    t8[r] = a;
                }
                float pmax = fmaxf(fmaxf(fmaxf(t8[0], t8[1]), fmaxf(t8[2], t8[3])),
                                   fmaxf(fmaxf(t8[4], t8[5]), fmaxf(t8[6], t8[7])));
                if (__any(pmax > mA + 11.0f)) {
                    pmax = fmaxf(pmax, __shfl_xor(pmax, 32, 64));
                    float mn = fmaxf(mA, pmax);
                    float fac = fexp2(mA - mn);
                    lsA *= fac; oA[0] *= fac; oA[1] *= fac; mA = mn;
                }
            }
            // ---- strip B softmax ----
            {
                float t8[8];
#pragma unroll
                for (int r = 0; r < 8; ++r)
                    t8[r] = fmaxf(fmaxf(sB[0][r], sB[0][r + 8]), fmaxf(sB[1][r], sB[1][r + 8]));
                float pmax = fmaxf(fmaxf(fmaxf(t8[0], t8[1]), fmaxf(t8[2], t8[3])),
                                   fmaxf(fmaxf(t8[4], t8[5]), fmaxf(t8[6], t8[7])));
                if (__any(pmax > mB + 11.0f)) {
                    pmax = fmaxf(pmax, __shfl_xor(pmax, 32, 64));
                    float mn = fmaxf(mB, pmax);
                    float fac = fexp2(mB - mn);
                    lsB *= fac; oB[0] *= fac; oB[1] *= fac; mB = mn;
                }
            }

            // ---- P = exp2(S - m), pack bf16 (both strips) ----
            unsigned uloA[8], uhiA[8], uloB[8], uhiB[8];
            {
                float rs = 0.f;
#pragma unroll
                for (int kt = 0; kt < 2; ++kt) {
#pragma unroll
                    for (int jj = 0; jj < 4; ++jj) {
                        if (kt < nktA) {
                            float p0 = fexp2(sA[kt][4 * jj + 0] - mA);
                            float p1 = fexp2(sA[kt][4 * jj + 1] - mA);
                            float p2 = fexp2(sA[kt][4 * jj + 2] - mA);
                            float p3 = fexp2(sA[kt][4 * jj + 3] - mA);
                            rs += (p0 + p1) + (p2 + p3);
                            uloA[4 * kt + jj] = pack_bf2(p0, p1);
                            uhiA[4 * kt + jj] = pack_bf2(p2, p3);
                        } else {
                            uloA[4 * kt + jj] = 0; uhiA[4 * kt + jj] = 0;
                        }
                    }
                }
                lsA += rs;
            }
            {
                float rs = 0.f;
#pragma unroll
                for (int kt = 0; kt < 2; ++kt) {
#pragma unroll
                    for (int jj = 0; jj < 4; ++jj) {
                        float p0 = fexp2(sB[kt][4 * jj + 0] - mB);
                        float p1 = fexp2(sB[kt][4 * jj + 1] - mB);
                        float p2 = fexp2(sB[kt][4 * jj + 2] - mB);
                        float p3 = fexp2(sB[kt][4 * jj + 3] - mB);
                        rs += (p0 + p1) + (p2 + p3);
                        uloB[4 * kt + jj] = pack_bf2(p0, p1);
                        uhiB[4 * kt + jj] = pack_bf2(p2, p3);
                    }
                }
                lsB += rs;
            }

            // ---- O^T += V^T P, shared V frags ----
            const int nksA = 2 * nktA;
#pragma unroll
            for (int ks = 0; ks < 4; ++ks) {
                short8 vf0 = *(const short8*)((const char*)vb_ + ofs[0][ks]);
                short8 vf1 = *(const short8*)((const char*)vb_ + ofs[1][ks]);
                uint2v rloB = __builtin_amdgcn_permlane32_swap(uloB[2 * ks], uloB[2 * ks + 1], false, false);
                uint2v rhiB = __builtin_amdgcn_permlane32_swap(uhiB[2 * ks], uhiB[2 * ks + 1], false, false);
                uint4v pwB; pwB[0] = rloB[0]; pwB[1] = rhiB[0]; pwB[2] = rloB[1]; pwB[3] = rhiB[1];
                short8 paB = __builtin_bit_cast(short8, pwB);
                if (ks < nksA) {
                    uint2v rloA = __builtin_amdgcn_permlane32_swap(uloA[2 * ks], uloA[2 * ks + 1], false, false);
                    uint2v rhiA = __builtin_amdgcn_permlane32_swap(uhiA[2 * ks], uhiA[2 * ks + 1], false, false);
                    uint4v pwA; pwA[0] = rloA[0]; pwA[1] = rhiA[0]; pwA[2] = rloA[1]; pwA[3] = rhiA[1];
                    short8 paA = __builtin_bit_cast(short8, pwA);
                    __builtin_amdgcn_s_setprio(1);
                    oA[0] = __builtin_amdgcn_mfma_f32_32x32x16_bf16(vf0, paA, oA[0], 0, 0, 0);
                    oA[1] = __builtin_amdgcn_mfma_f32_32x32x16_bf16(vf1, paA, oA[1], 0, 0, 0);
                    oB[0] = __builtin_amdgcn_mfma_f32_32x32x16_bf16(vf0, paB, oB[0], 0, 0, 0);
                    oB[1] = __builtin_amdgcn_mfma_f32_32x32x16_bf16(vf1, paB, oB[1], 0, 0, 0);
                    __builtin_amdgcn_s_setprio(0);
                } else {
                    __builtin_amdgcn_s_setprio(1);
                    oB[0] = __builtin_amdgcn_mfma_f32_32x32x16_bf16(vf0, paB, oB[0], 0, 0, 0);
                    oB[1] = __builtin_amdgcn_mfma_f32_32x32x16_bf16(vf1, paB, oB[1], 0, 0, 0);
                    __builtin_amdgcn_s_setprio(0);
                }
            }
        }
        cur = (cur == 2) ? 0 : cur + 1;
        nxt2 = (nxt2 == 2) ? 0 : nxt2 + 1;
    }
#undef STAGE

    lsA += __shfl_xor(lsA, 32, 64);
    lsB += __shfl_xor(lsB, 32, 64);

    const int lrA = 64 * w + q, lrB = lrA + 32;
    if (nch == 1) {
        float* op = outg + (long)b * TT * HD;
        const float invA = 1.f / lsA, invB = 1.f / lsB;
#pragma unroll
        for (int dt = 0; dt < 2; ++dt) {
#pragma unroll
            for (int jj = 0; jj < 4; ++jj) {
                f32x4 a4, b4;
                a4[0] = oA[dt][4 * jj + 0] * invA; a4[1] = oA[dt][4 * jj + 1] * invA;
                a4[2] = oA[dt][4 * jj + 2] * invA; a4[3] = oA[dt][4 * jj + 3] * invA;
                b4[0] = oB[dt][4 * jj + 0] * invB; b4[1] = oB[dt][4 * jj + 1] * invB;
                b4[2] = oB[dt][4 * jj + 2] * invB; b4[3] = oB[dt][4 * jj + 3] * invB;
                *(f32x4*)(op + (long)rA * HD + 32 * dt + 8 * jj + 4 * hi) = a4;
                *(f32x4*)(op + (long)rB * HD + 32 * dt + 8 * jj + 4 * hi) = b4;
            }
        }
    } else {
        const float invA = lsA > 0.f ? 1.f / lsA : 0.f;
        const float invB = lsB > 0.f ? 1.f / lsB : 0.f;
        unsigned short* poA = Opart + ((long)(b * 80 + j) * 128 + lrA) * 64;
        unsigned short* poB = Opart + ((long)(b * 80 + j) * 128 + lrB) * 64;
#pragma unroll
        for (int dt = 0; dt < 2; ++dt) {
#pragma unroll
            for (int jj = 0; jj < 4; ++jj) {
                uint2v ua, ub;
                ua[0] = pack_bf2(oA[dt][4 * jj + 0] * invA, oA[dt][4 * jj + 1] * invA);
                ua[1] = pack_bf2(oA[dt][4 * jj + 2] * invA, oA[dt][4 * jj + 3] * invA);
                ub[0] = pack_bf2(oB[dt][4 * jj + 0] * invB, oB[dt][4 * jj + 1] * invB);
                ub[1] = pack_bf2(oB[dt][4 * jj + 2] * invB, oB[dt][4 * jj + 3] * invB);
                *(uint2v*)(poA + 32 * dt + 8 * jj + 4 * hi) = ua;
                *(uint2v*)(poB + 32 * dt + 8 * jj + 4 * hi) = ub;
            }
        }
        ml[(long)(b * 80 + j) * 128 + lrA] = make_float2(mA, lsA);
        ml[(long)(b * 80 + j) * 128 + lrB] = make_float2(mB, lsB);
    }
}

// ---------------- Kernel 3: combine partials (qt >= 8; exp2 domain) ----------------
__global__ __launch_bounds__(256) void combine(
    const unsigned short* __restrict__ Opart,
    const float2* __restrict__ ml,
    float* __restrict__ outg)
{
    const int bid = blockIdx.x;            // 192 = 8b x 24qt
    const int b = bid & 7, qt = 8 + (bid >> 3);
    const int nc = (2 * qt + 17) >> 4;     // 2..4
    int jb = 0;
    for (int qq = 31; qq > qt; --qq) jb += (2 * qq + 17) >> 4;

    const int tid = threadIdx.x;
    const int row = tid >> 1, dh = (tid & 1) * 32;
    const long base = (long)(b * 80 + jb) * 128 + row;

    float mv[4], lv[4], M = -INFINITY;
#pragma unroll
    for (int c = 0; c < 4; ++c) {
        mv[c] = -INFINITY; lv[c] = 0.f;
        if (c < nc) {
            float2 t = ml[base + (long)c * 128];
            mv[c] = t.x; lv[c] = t.y;
            M = fmaxf(M, mv[c]);
        }
    }
    float L = 0.f, wt[4];
#pragma unroll
    for (int c = 0; c < 4; ++c) {
        wt[c] = (c < nc) ? lv[c] * fexp2(mv[c] - M) : 0.f;
        L += wt[c];
    }
    float acc[32];
#pragma unroll
    for (int i = 0; i < 32; ++i) acc[i] = 0.f;
#pragma unroll
    for (int c = 0; c < 4; ++c) {
        if (c < nc && wt[c] > 0.f) {
            const short8* op = (const short8*)(Opart + (base + (long)c * 128) * 64 + dh);
#pragma unroll
            for (int i = 0; i < 4; ++i) {
                short8 v = op[i];
#pragma unroll
                for (int e = 0; e < 8; ++e)
                    acc[8 * i + e] += wt[c] * bf2f((unsigned short)v[e]);
            }
        }
    }
    const float invL = 1.f / L;
    float* dst = outg + ((long)b * TT + qt * 128 + row) * HD + dh;
#pragma unroll
    for (int i = 0; i < 8; ++i) {
        f32x4 o;
        o[0] = acc[4 * i + 0] * invL; o[1] = acc[4 * i + 1] * invL;
        o[2] = acc[4 * i + 2] * invL; o[3] = acc[4 * i + 3] * invL;
        *(f32x4*)(dst + 4 * i) = o;
    }
}

extern "C" void kernel_launch(void* const* d_in, const int* in_sizes, int n_in,
                              void* d_out, int out_size, void* d_ws, size_t ws_size,
                              hipStream_t stream) {
    const float* x  = (const float*)d_in[0];
    const float* Wk = (const float*)d_in[1];
    const float* Wq = (const float*)d_in[2];
    const float* Wv = (const float*)d_in[3];
    float* out = (float*)d_out;

    const long N = (long)BB * TT * HD;
    unsigned short* q16 = (unsigned short*)d_ws;
    unsigned short* k16 = q16 + N;
    unsigned short* vt16 = k16 + N;
    unsigned short* Opart = (unsigned short*)((char*)d_ws + 12 * 1024 * 1024);  // 10.5 MB
    float2* mlp = (float2*)((char*)d_ws + 23068672);                            // 0.66 MB

    qkv_proj_mfma<<<BB * TT / 128, 256, 0, stream>>>(x, Wk, Wq, Wv, q16, k16, vt16);
    attn_mfma<<<8 * 80, 128, 0, stream>>>(q16, k16, vt16, Opart, mlp, out);
    combine<<<8 * 24, 256, 0, stream>>>(Opart, mlp, out);
}

// Round 13
// 70.030 us; speedup vs baseline: 1.0762x; 1.0762x over previous
//
#include <hip/hip_runtime.h>
#include <hip/hip_bf16.h>
#include <math.h>

#define BB 8
#define TT 4096
#define HD 64

typedef __attribute__((ext_vector_type(8))) short short8;
typedef __attribute__((ext_vector_type(4))) float f32x4;
typedef __attribute__((ext_vector_type(16))) float f32x16;
typedef __attribute__((ext_vector_type(2))) unsigned int uint2v;
typedef __attribute__((ext_vector_type(4))) unsigned int uint4v;

#define LOG2E 1.44269504088896f

// 1-inst packed f32->bf16 (RNE). src0 -> lo, src1 -> hi (matches a | b<<16).
__device__ __forceinline__ unsigned pack_bf2(float a, float b) {
    unsigned r;
    asm("v_cvt_pk_bf16_f32 %0, %1, %2" : "=v"(r) : "v"(a), "v"(b));
    return r;
}
__device__ __forceinline__ unsigned short bfbits(float f) {
    unsigned r;
    asm("v_cvt_pk_bf16_f32 %0, %1, %2" : "=v"(r) : "v"(f), "v"(f));
    return (unsigned short)r;
}
__device__ __forceinline__ float bf2f(unsigned short u) {
    unsigned v = (unsigned)u << 16;
    return __builtin_bit_cast(float, v);
}
__device__ __forceinline__ float fexp2(float x) {     // raw v_exp_f32
    return __builtin_amdgcn_exp2f(x);
}
__device__ __forceinline__ short8 cvt8(float4 a, float4 b, float sc) {
    uint4v u;
    u[0] = pack_bf2(a.x * sc, a.y * sc);
    u[1] = pack_bf2(a.z * sc, a.w * sc);
    u[2] = pack_bf2(b.x * sc, b.y * sc);
    u[3] = pack_bf2(b.z * sc, b.w * sc);
    return __builtin_bit_cast(short8, u);
}

// ---------------- Kernel 1: MFMA QKV projection ----------------
// V^T now bounced through LDS -> coalesced 16B stores (was: 32 scalar 2B
// scattered stores per thread). LDS phase-reuse: stage{xls,wls} -> bounce{cb,vb}.
__global__ __launch_bounds__(256) void qkv_proj_mfma(
    const float* __restrict__ x,
    const float* __restrict__ Wk, const float* __restrict__ Wq, const float* __restrict__ Wv,
    unsigned short* __restrict__ qo, unsigned short* __restrict__ ko,
    unsigned short* __restrict__ vto)
{
    __shared__ short lds[26112];          // 52 KB
    short* xls = lds;                     // phase 1: [0, 8192)
    short* wls = lds + 8192;              // phase 1: [8192, 20480)

    const int tid = threadIdx.x;
    const int l = tid & 63, w = tid >> 6;
    const int hi = l >> 5, c31 = l & 31;
    const long t0 = (long)blockIdx.x * 128;
    const int b = (int)(t0 >> 12);
    const int tl0 = (int)(t0 & 4095);

#pragma unroll
    for (int i = 0; i < 4; ++i) {
        int slot = tid + 256 * i;
        int row = slot >> 3, bl = slot & 7;
        const float* xp = x + (t0 + row) * 64 + 8 * bl;
        float4 a = *(const float4*)xp;
        float4 bq = *(const float4*)(xp + 4);
        *(short8*)&xls[row * 64 + 8 * (bl ^ (row & 7))] = cvt8(a, bq, 1.f);
    }
#pragma unroll
    for (int i = 0; i < 6; ++i) {
        int slot = tid + 256 * i;
        int row = slot >> 3, bl = slot & 7;
        const float* wp;
        float sc;
        if (row < 64)       { wp = Wq + row * 64;         sc = 0.125f * LOG2E; }
        else if (row < 128) { wp = Wk + (row - 64) * 64;  sc = 1.f; }
        else                { wp = Wv + (row - 128) * 64; sc = 1.f; }
        wp += 8 * bl;
        float4 a = *(const float4*)wp;
        float4 bq = *(const float4*)(wp + 4);
        *(short8*)&wls[row * 64 + 8 * (bl ^ (row & 7))] = cvt8(a, bq, sc);
    }
    __syncthreads();

    short8 xf[4];
#pragma unroll
    for (int ki = 0; ki < 4; ++ki) {
        int row = 32 * w + c31;
        xf[ki] = *(const short8*)&xls[row * 64 + 8 * ((2 * ki + hi) ^ (row & 7))];
    }
    f32x16 cqk[4] = {};
#pragma unroll
    for (int nt = 0; nt < 4; ++nt) {
#pragma unroll
        for (int ki = 0; ki < 4; ++ki) {
            int row = 32 * nt + c31;
            short8 wf = *(const short8*)&wls[row * 64 + 8 * ((2 * ki + hi) ^ (row & 7))];
            cqk[nt] = __builtin_amdgcn_mfma_f32_32x32x16_bf16(xf[ki], wf, cqk[nt], 0, 0, 0);
        }
    }
    f32x16 cv[2] = {};
#pragma unroll
    for (int rt = 0; rt < 2; ++rt) {
#pragma unroll
        for (int ki = 0; ki < 4; ++ki) {
            int row = 128 + 32 * rt + c31;
            short8 wf = *(const short8*)&wls[row * 64 + 8 * ((2 * ki + hi) ^ (row & 7))];
            cv[rt] = __builtin_amdgcn_mfma_f32_32x32x16_bf16(wf, xf[ki], cv[rt], 0, 0, 0);
        }
    }

    __syncthreads();                      // done reading xls/wls
    short* cb = lds;                      // phase 2: q,k bounce [0, 17408) : 128 x 136
    short* vb = lds + 17408;              // phase 2: v bounce  [17408, 26112) : 64 x 136
#pragma unroll
    for (int nt = 0; nt < 4; ++nt) {
#pragma unroll
        for (int r = 0; r < 16; ++r) {
            int trow = 32 * w + (r & 3) + 8 * (r >> 2) + 4 * hi;
            cb[trow * 136 + 32 * nt + c31] = (short)bfbits(cqk[nt][r]);
        }
    }
#pragma unroll
    for (int rt = 0; rt < 2; ++rt) {
#pragma unroll
        for (int r = 0; r < 16; ++r) {
            int h = 32 * rt + (r & 3) + 8 * (r >> 2) + 4 * hi;
            vb[h * 136 + 32 * w + c31] = (short)bfbits(cv[rt][r]);
        }
    }
    __syncthreads();
    {
        int row = tid >> 1, seg = tid & 1;
        const short8* cp = (const short8*)&cb[row * 136 + seg * 64];
        unsigned short* dst = (seg == 0 ? qo : ko) + (t0 + row) * 64;
#pragma unroll
        for (int i = 0; i < 8; ++i) ((short8*)dst)[i] = cp[i];
    }
    // V^T coalesced stores: slot -> (h, 16B t-chunk); 16-lane groups contiguous
#pragma unroll
    for (int i = 0; i < 4; ++i) {
        int slot = tid + 256 * i;
        int h = slot >> 4, tc = slot & 15;
        short8 vv = *(const short8*)&vb[h * 136 + 8 * tc];
        *(short8*)(vto + ((long)b * 64 + h) * 4096 + tl0 + 8 * tc) = vv;
    }
}

// ---------------- Kernel 2: MFMA flash attention, paired-tile (128-wide KV step) ----------------
// Round-11 shell (256 thr = 4 waves x 32 q-rows, chunk 16, grid 640) with tiles
// processed in PAIRS: QK(t) & QK(t+1) independent -> joint max -> ONE m-update ->
// exp/pack/PV(t) -> exp/pack/PV(t+1). Halves barriers-per-work, waits, loop
// overhead; doubles MFMA ILP; PV(t) overlaps exp(t+1). 4 LDS buffers (64 KB).
__global__ __launch_bounds__(256, 2) void attn_mfma(
    const unsigned short* __restrict__ qg,
    const unsigned short* __restrict__ kg,
    const unsigned short* __restrict__ vtg,
    unsigned short* __restrict__ Opart,
    float2* __restrict__ ml,
    float* __restrict__ outg)
{
    __shared__ short kls[4][4096];
    __shared__ short vls[4][4096];

    const int tid = threadIdx.x;
    const int l = tid & 63, w = tid >> 6;     // w in {0..3}
    const int q = l & 31, hi = l >> 5;
    const int qs7 = q & 7;

    const int bid = blockIdx.x;
    const int b = bid & 7;
    const int j = bid >> 3;
    int qt = 0, ci = 0;
    {
        int acc = 0;
        for (int qq = 31; qq >= 0; --qq) {       // descending size (LPT)
            int nc = (2 * qq + 17) >> 4;
            if (j < acc + nc) { qt = qq; ci = j - acc; break; }
            acc += nc;
        }
    }
    const int nch = (2 * qt + 17) >> 4;
    int ntile = 2 * qt + 2 - 16 * ci;          // always even
    if (ntile > 16) ntile = 16;
    const int c0 = ci * 1024;

    const int q0w = qt * 128 + 32 * w;
    const int qr = q0w + q;
    const int lastg = (q0w + 31) >> 6;         // wave's diagonal KV tile (global idx)

    const unsigned short* qb = qg + ((long)b * TT + qr) * HD;
    short8 qf[4];
#pragma unroll
    for (int ki = 0; ki < 4; ++ki) qf[ki] = *(const short8*)(qb + 16 * ki + 8 * hi);

    int ofs[2][4];
#pragma unroll
    for (int a = 0; a < 2; ++a)
#pragma unroll
        for (int i2 = 0; i2 < 4; ++i2)
            ofs[a][i2] = (32 * a + q) * 128 + 16 * ((2 * i2 + hi) ^ qs7);

    f32x16 oacc[2] = {};
    float m = -INFINITY, lsum = 0.f;           // lsum: own-half partial

    const unsigned short* kbase = kg + (long)b * TT * HD;
    const unsigned short* vbase = vtg + (long)b * HD * TT;

    const int r8 = l >> 3;
    const int blsw = (l & 7) ^ r8;
    const long koff0 = (long)(8 * w + r8) * HD + 8 * blsw;
    const long voff0 = (long)(8 * w + r8) * TT + 8 * blsw;

#define STAGE(buf_, s_) do {                                                            \
    _Pragma("unroll")                                                                   \
    for (int c_ = 0; c_ < 2; ++c_) {                                                    \
        const unsigned short* kp_ = kbase + (long)(s_) * HD + koff0 + (long)c_ * 32 * HD; \
        const unsigned short* vp_ = vbase + (s_) + voff0 + (long)c_ * 32 * TT;          \
        short* kd_ = &kls[buf_][2048 * c_ + 512 * w];                                   \
        short* vd_ = &vls[buf_][2048 * c_ + 512 * w];                                   \
        __builtin_amdgcn_global_load_lds((const __attribute__((address_space(1))) void*)kp_, \
                                         (__attribute__((address_space(3))) void*)kd_, 16, 0, 0); \
        __builtin_amdgcn_global_load_lds((const __attribute__((address_space(1))) void*)vp_, \
                                         (__attribute__((address_space(3))) void*)vd_, 16, 0, 0); \
    }                                                                                   \
} while (0)

    // prologue: pair0 -> slot0 (bufs 0,1); pair1 -> slot1 (bufs 2,3)
    STAGE(0, c0); STAGE(1, c0 + 64);
    if (ntile > 2) { STAGE(2, c0 + 128); STAGE(3, c0 + 192); }

    const int npairs = ntile >> 1;
    for (int p = 0; p < npairs; ++p) {
        const int sA = c0 + (p << 7);
        // counted drain: pair p's 8 loads done; pair p+1's 8 may fly
        if (p + 1 < npairs) asm volatile("s_waitcnt vmcnt(8)" ::: "memory");
        else                asm volatile("s_waitcnt vmcnt(0)" ::: "memory");
        __builtin_amdgcn_s_barrier();          // all waves' pair-p loads visible
        __builtin_amdgcn_sched_barrier(0);

        const int bs = (p & 1) << 1;           // buffer slot base
        const short* kbA = kls[bs],     *vbA = vls[bs];
        const short* kbB = kls[bs + 1], *vbB = vls[bs + 1];
        const int gtiA = ci * 16 + 2 * p, gtiB = gtiA + 1;
        const bool doA = (sA <= q0w + 31);
        const bool doB = (sA + 64 <= q0w + 31);

        if (doA) {
            const int nktA = (gtiA == lastg && (w & 1) == 0) ? 1 : 2;
            const int nktB = (gtiB == lastg && (w & 1) == 0) ? 1 : 2;

            // ---- QK^T for both sub-tiles (independent MFMA chains) ----
            f32x16 sacA[2] = {}, sacB[2] = {};
            __builtin_amdgcn_s_setprio(1);
#pragma unroll
            for (int kt = 0; kt < 2; ++kt) {
                if (kt < nktA) {
#pragma unroll
                    for (int ki = 0; ki < 4; ++ki) {
                        short8 kf = *(const short8*)((const char*)kbA + ofs[kt][ki]);
                        sacA[kt] = __builtin_amdgcn_mfma_f32_32x32x16_bf16(kf, qf[ki], sacA[kt], 0, 0, 0);
                    }
                }
            }
            if (doB) {
#pragma unroll
                for (int kt = 0; kt < 2; ++kt) {
                    if (kt < nktB) {
#pragma unroll
                        for (int ki = 0; ki < 4; ++ki) {
                            short8 kf = *(const short8*)((const char*)kbB + ofs[kt][ki]);
                            sacB[kt] = __builtin_amdgcn_mfma_f32_32x32x16_bf16(kf, qf[ki], sacB[kt], 0, 0, 0);
                        }
                    }
                }
            }
            __builtin_amdgcn_s_setprio(0);

            // ---- causal masks (diag sub-tile only) ----
            if (gtiA == lastg) {
#pragma unroll
                for (int kt = 0; kt < 2; ++kt) {
                    if (kt >= nktA) continue;
#pragma unroll
                    for (int r = 0; r < 16; ++r) {
                        int kkg = sA + 32 * kt + (r & 3) + 8 * (r >> 2) + 4 * hi;
                        if (kkg > qr) sacA[kt][r] = -INFINITY;
                    }
                }
            }
            if (doB && gtiB == lastg) {
#pragma unroll
                for (int kt = 0; kt < 2; ++kt) {
                    if (kt >= nktB) continue;
#pragma unroll
                    for (int r = 0; r < 16; ++r) {
                        int kkg = sA + 64 + 32 * kt + (r & 3) + 8 * (r >> 2) + 4 * hi;
                        if (kkg > qr) sacB[kt][r] = -INFINITY;
                    }
                }
            }

            // ---- joint lane-local tree max over both sub-tiles ----
            float t8[8];
#pragma unroll
            for (int r = 0; r < 8; ++r) {
                float a = fmaxf(sacA[0][r], sacA[0][r + 8]);
                if (nktA == 2) a = fmaxf(a, fmaxf(sacA[1][r], sacA[1][r + 8]));
                if (doB) {
                    a = fmaxf(a, fmaxf(sacB[0][r], sacB[0][r + 8]));
                    if (nktB == 2) a = fmaxf(a, fmaxf(sacB[1][r], sacB[1][r + 8]));
                }
                t8[r] = a;
            }
            float pmax = fmaxf(fmaxf(fmaxf(t8[0], t8[1]), fmaxf(t8[2], t8[3])),
                               fmaxf(fmaxf(t8[4], t8[5]), fmaxf(t8[6], t8[7])));
            if (__any(pmax > m + 11.0f)) {     // single m-update per pair
                pmax = fmaxf(pmax, __shfl_xor(pmax, 32, 64));
                float mn = fmaxf(m, pmax);
                float fac = fexp2(m - mn);
                lsum *= fac;
                oacc[0] *= fac;
                oacc[1] *= fac;
                m = mn;
            }

            // ---- sub-tile A: exp + pack + PV ----
            {
                float rs = 0.f;
                unsigned ulo[8], uhi[8];
#pragma unroll
                for (int kt = 0; kt < 2; ++kt) {
#pragma unroll
                    for (int jj = 0; jj < 4; ++jj) {
                        if (kt < nktA) {
                            float p0 = fexp2(sacA[kt][4 * jj + 0] - m);
                            float p1 = fexp2(sacA[kt][4 * jj + 1] - m);
                            float p2 = fexp2(sacA[kt][4 * jj + 2] - m);
                            float p3 = fexp2(sacA[kt][4 * jj + 3] - m);
                            rs += (p0 + p1) + (p2 + p3);
                            ulo[4 * kt + jj] = pack_bf2(p0, p1);
                            uhi[4 * kt + jj] = pack_bf2(p2, p3);
                        } else {
                            ulo[4 * kt + jj] = 0; uhi[4 * kt + jj] = 0;
                        }
                    }
                }
                lsum += rs;
                const int nks = 2 * nktA;
#pragma unroll
                for (int ks = 0; ks < 4; ++ks) {
                    if (ks >= nks) continue;
                    uint2v rlo = __builtin_amdgcn_permlane32_swap(ulo[2 * ks], ulo[2 * ks + 1], false, false);
                    uint2v rhi = __builtin_amdgcn_permlane32_swap(uhi[2 * ks], uhi[2 * ks + 1], false, false);
                    uint4v paw;
                    paw[0] = rlo[0]; paw[1] = rhi[0]; paw[2] = rlo[1]; paw[3] = rhi[1];
                    short8 pa = __builtin_bit_cast(short8, paw);
                    __builtin_amdgcn_s_setprio(1);
#pragma unroll
                    for (int dt = 0; dt < 2; ++dt) {
                        short8 vf = *(const short8*)((const char*)vbA + ofs[dt][ks]);
                        oacc[dt] = __builtin_amdgcn_mfma_f32_32x32x16_bf16(vf, pa, oacc[dt], 0, 0, 0);
                    }
                    __builtin_amdgcn_s_setprio(0);
                }
            }
            // ---- sub-tile B: exp + pack + PV (overlaps A's PV MFMAs) ----
            if (doB) {
                float rs = 0.f;
                unsigned ulo[8], uhi[8];
#pragma unroll
                for (int kt = 0; kt < 2; ++kt) {
#pragma unroll
                    for (int jj = 0; jj < 4; ++jj) {
                        if (kt < nktB) {
                            float p0 = fexp2(sacB[kt][4 * jj + 0] - m);
                            float p1 = fexp2(sacB[kt][4 * jj + 1] - m);
                            float p2 = fexp2(sacB[kt][4 * jj + 2] - m);
                            float p3 = fexp2(sacB[kt][4 * jj + 3] - m);
                            rs += (p0 + p1) + (p2 + p3);
                            ulo[4 * kt + jj] = pack_bf2(p0, p1);
                            uhi[4 * kt + jj] = pack_bf2(p2, p3);
                        } else {
                            ulo[4 * kt + jj] = 0; uhi[4 * kt + jj] = 0;
                        }
                    }
                }
                lsum += rs;
                const int nks = 2 * nktB;
#pragma unroll
                for (int ks = 0; ks < 4; ++ks) {
                    if (ks >= nks) continue;
                    uint2v rlo = __builtin_amdgcn_permlane32_swap(ulo[2 * ks], ulo[2 * ks + 1], false, false);
                    uint2v rhi = __builtin_amdgcn_permlane32_swap(uhi[2 * ks], uhi[2 * ks + 1], false, false);
                    uint4v paw;
                    paw[0] = rlo[0]; paw[1] = rhi[0]; paw[2] = rlo[1]; paw[3] = rhi[1];
                    short8 pa = __builtin_bit_cast(short8, paw);
                    __builtin_amdgcn_s_setprio(1);
#pragma unroll
                    for (int dt = 0; dt < 2; ++dt) {
                        short8 vf = *(const short8*)((const char*)vbB + ofs[dt][ks]);
                        oacc[dt] = __builtin_amdgcn_mfma_f32_32x32x16_bf16(vf, pa, oacc[dt], 0, 0, 0);
                    }
                    __builtin_amdgcn_s_setprio(0);
                }
            }
        }

        __builtin_amdgcn_s_barrier();          // all waves done reading slot bs
        if (p + 2 < npairs) { STAGE(bs, sA + 256); STAGE(bs + 1, sA + 320); }
    }
#undef STAGE

    lsum += __shfl_xor(lsum, 32, 64);          // combine per-half sums once

    const int lr = 32 * w + q;
    if (nch == 1) {
        const float inv = 1.f / lsum;
        float* op = outg + ((long)b * TT + qr) * HD;
#pragma unroll
        for (int dt = 0; dt < 2; ++dt) {
#pragma unroll
            for (int jj = 0; jj < 4; ++jj) {
                f32x4 o4;
                o4[0] = oacc[dt][4 * jj + 0] * inv;
                o4[1] = oacc[dt][4 * jj + 1] * inv;
                o4[2] = oacc[dt][4 * jj + 2] * inv;
                o4[3] = oacc[dt][4 * jj + 3] * inv;
                *(f32x4*)(op + 32 * dt + 8 * jj + 4 * hi) = o4;
            }
        }
    } else {
        const float inv = lsum > 0.f ? 1.f / lsum : 0.f;
        unsigned short* po = Opart + ((long)(b * 80 + j) * 128 + lr) * 64;
#pragma unroll
        for (int dt = 0; dt < 2; ++dt) {
#pragma unroll
            for (int jj = 0; jj < 4; ++jj) {
                uint2v u;
                u[0] = pack_bf2(oacc[dt][4 * jj + 0] * inv, oacc[dt][4 * jj + 1] * inv);
                u[1] = pack_bf2(oacc[dt][4 * jj + 2] * inv, oacc[dt][4 * jj + 3] * inv);
                *(uint2v*)(po + 32 * dt + 8 * jj + 4 * hi) = u;
            }
        }
        ml[(long)(b * 80 + j) * 128 + lr] = make_float2(m, lsum);
    }
}

// ---------------- Kernel 3: combine partials (qt >= 8; exp2 domain) ----------------
__global__ __launch_bounds__(256) void combine(
    const unsigned short* __restrict__ Opart,
    const float2* __restrict__ ml,
    float* __restrict__ outg)
{
    const int bid = blockIdx.x;            // 192 = 8b x 24qt
    const int b = bid & 7, qt = 8 + (bid >> 3);
    const int nc = (2 * qt + 17) >> 4;     // 2..4
    int jb = 0;
    for (int qq = 31; qq > qt; --qq) jb += (2 * qq + 17) >> 4;

    const int tid = threadIdx.x;
    const int row = tid >> 1, dh = (tid & 1) * 32;
    const long base = (long)(b * 80 + jb) * 128 + row;

    float mv[4], lv[4], M = -INFINITY;
#pragma unroll
    for (int c = 0; c < 4; ++c) {
        mv[c] = -INFINITY; lv[c] = 0.f;
        if (c < nc) {
            float2 t = ml[base + (long)c * 128];
            mv[c] = t.x; lv[c] = t.y;
            M = fmaxf(M, mv[c]);
        }
    }
    float L = 0.f, wt[4];
#pragma unroll
    for (int c = 0; c < 4; ++c) {
        wt[c] = (c < nc) ? lv[c] * fexp2(mv[c] - M) : 0.f;
        L += wt[c];
    }
    float acc[32];
#pragma unroll
    for (int i = 0; i < 32; ++i) acc[i] = 0.f;
#pragma unroll
    for (int c = 0; c < 4; ++c) {
        if (c < nc && wt[c] > 0.f) {
            const short8* op = (const short8*)(Opart + (base + (long)c * 128) * 64 + dh);
#pragma unroll
            for (int i = 0; i < 4; ++i) {
                short8 v = op[i];
#pragma unroll
                for (int e = 0; e < 8; ++e)
                    acc[8 * i + e] += wt[c] * bf2f((unsigned short)v[e]);
            }
        }
    }
    const float invL = 1.f / L;
    float* dst = outg + ((long)b * TT + qt * 128 + row) * HD + dh;
#pragma unroll
    for (int i = 0; i < 8; ++i) {
        f32x4 o;
        o[0] = acc[4 * i + 0] * invL; o[1] = acc[4 * i + 1] * invL;
        o[2] = acc[4 * i + 2] * invL; o[3] = acc[4 * i + 3] * invL;
        *(f32x4*)(dst + 4 * i) = o;
    }
}

extern "C" void kernel_launch(void* const* d_in, const int* in_sizes, int n_in,
                              void* d_out, int out_size, void* d_ws, size_t ws_size,
                              hipStream_t stream) {
    const float* x  = (const float*)d_in[0];
    const float* Wk = (const float*)d_in[1];
    const float* Wq = (const float*)d_in[2];
    const float* Wv = (const float*)d_in[3];
    float* out = (float*)d_out;

    const long N = (long)BB * TT * HD;
    unsigned short* q16 = (unsigned short*)d_ws;
    unsigned short* k16 = q16 + N;
    unsigned short* vt16 = k16 + N;
    unsigned short* Opart = (unsigned short*)((char*)d_ws + 12 * 1024 * 1024);  // 10.5 MB
    float2* mlp = (float2*)((char*)d_ws + 23068672);                            // 0.66 MB

    qkv_proj_mfma<<<BB * TT / 128, 256, 0, stream>>>(x, Wk, Wq, Wv, q16, k16, vt16);
    attn_mfma<<<8 * 80, 256, 0, stream>>>(q16, k16, vt16, Opart, mlp, out);
    combine<<<8 * 24, 256, 0, stream>>>(Opart, mlp, out);
}

// Round 14
// 61.159 us; speedup vs baseline: 1.2323x; 1.1451x over previous
//
#include <hip/hip_runtime.h>
#include <hip/hip_bf16.h>
#include <math.h>

#define BB 8
#define TT 4096
#define HD 64

typedef __attribute__((ext_vector_type(8))) short short8;
typedef __attribute__((ext_vector_type(4))) float f32x4;
typedef __attribute__((ext_vector_type(16))) float f32x16;
typedef __attribute__((ext_vector_type(2))) unsigned int uint2v;
typedef __attribute__((ext_vector_type(4))) unsigned int uint4v;

#define LOG2E 1.44269504088896f

// 1-inst packed f32->bf16 (RNE). src0 -> lo, src1 -> hi (matches a | b<<16).
__device__ __forceinline__ unsigned pack_bf2(float a, float b) {
    unsigned r;
    asm("v_cvt_pk_bf16_f32 %0, %1, %2" : "=v"(r) : "v"(a), "v"(b));
    return r;
}
__device__ __forceinline__ unsigned short bfbits(float f) {
    unsigned r;
    asm("v_cvt_pk_bf16_f32 %0, %1, %2" : "=v"(r) : "v"(f), "v"(f));
    return (unsigned short)r;
}
__device__ __forceinline__ float bf2f(unsigned short u) {
    unsigned v = (unsigned)u << 16;
    return __builtin_bit_cast(float, v);
}
__device__ __forceinline__ float fexp2(float x) {     // raw v_exp_f32
    return __builtin_amdgcn_exp2f(x);
}
__device__ __forceinline__ short8 cvt8(float4 a, float4 b, float sc) {
    uint4v u;
    u[0] = pack_bf2(a.x * sc, a.y * sc);
    u[1] = pack_bf2(a.z * sc, a.w * sc);
    u[2] = pack_bf2(b.x * sc, b.y * sc);
    u[3] = pack_bf2(b.z * sc, b.w * sc);
    return __builtin_bit_cast(short8, u);
}

// ---------------- Kernel 1: MFMA QKV projection (R13 version: V LDS-bounced) ----------------
__global__ __launch_bounds__(256) void qkv_proj_mfma(
    const float* __restrict__ x,
    const float* __restrict__ Wk, const float* __restrict__ Wq, const float* __restrict__ Wv,
    unsigned short* __restrict__ qo, unsigned short* __restrict__ ko,
    unsigned short* __restrict__ vto)
{
    __shared__ short lds[26112];          // 52 KB
    short* xls = lds;
    short* wls = lds + 8192;

    const int tid = threadIdx.x;
    const int l = tid & 63, w = tid >> 6;
    const int hi = l >> 5, c31 = l & 31;
    const long t0 = (long)blockIdx.x * 128;
    const int b = (int)(t0 >> 12);
    const int tl0 = (int)(t0 & 4095);

#pragma unroll
    for (int i = 0; i < 4; ++i) {
        int slot = tid + 256 * i;
        int row = slot >> 3, bl = slot & 7;
        const float* xp = x + (t0 + row) * 64 + 8 * bl;
        float4 a = *(const float4*)xp;
        float4 bq = *(const float4*)(xp + 4);
        *(short8*)&xls[row * 64 + 8 * (bl ^ (row & 7))] = cvt8(a, bq, 1.f);
    }
#pragma unroll
    for (int i = 0; i < 6; ++i) {
        int slot = tid + 256 * i;
        int row = slot >> 3, bl = slot & 7;
        const float* wp;
        float sc;
        if (row < 64)       { wp = Wq + row * 64;         sc = 0.125f * LOG2E; }
        else if (row < 128) { wp = Wk + (row - 64) * 64;  sc = 1.f; }
        else                { wp = Wv + (row - 128) * 64; sc = 1.f; }
        wp += 8 * bl;
        float4 a = *(const float4*)wp;
        float4 bq = *(const float4*)(wp + 4);
        *(short8*)&wls[row * 64 + 8 * (bl ^ (row & 7))] = cvt8(a, bq, sc);
    }
    __syncthreads();

    short8 xf[4];
#pragma unroll
    for (int ki = 0; ki < 4; ++ki) {
        int row = 32 * w + c31;
        xf[ki] = *(const short8*)&xls[row * 64 + 8 * ((2 * ki + hi) ^ (row & 7))];
    }
    f32x16 cqk[4] = {};
#pragma unroll
    for (int nt = 0; nt < 4; ++nt) {
#pragma unroll
        for (int ki = 0; ki < 4; ++ki) {
            int row = 32 * nt + c31;
            short8 wf = *(const short8*)&wls[row * 64 + 8 * ((2 * ki + hi) ^ (row & 7))];
            cqk[nt] = __builtin_amdgcn_mfma_f32_32x32x16_bf16(xf[ki], wf, cqk[nt], 0, 0, 0);
        }
    }
    f32x16 cv[2] = {};
#pragma unroll
    for (int rt = 0; rt < 2; ++rt) {
#pragma unroll
        for (int ki = 0; ki < 4; ++ki) {
            int row = 128 + 32 * rt + c31;
            short8 wf = *(const short8*)&wls[row * 64 + 8 * ((2 * ki + hi) ^ (row & 7))];
            cv[rt] = __builtin_amdgcn_mfma_f32_32x32x16_bf16(wf, xf[ki], cv[rt], 0, 0, 0);
        }
    }

    __syncthreads();
    short* cb = lds;                      // [0, 17408): 128 x 136 q,k bounce
    short* vb = lds + 17408;              // [17408, 26112): 64 x 136 v bounce
#pragma unroll
    for (int nt = 0; nt < 4; ++nt) {
#pragma unroll
        for (int r = 0; r < 16; ++r) {
            int trow = 32 * w + (r & 3) + 8 * (r >> 2) + 4 * hi;
            cb[trow * 136 + 32 * nt + c31] = (short)bfbits(cqk[nt][r]);
        }
    }
#pragma unroll
    for (int rt = 0; rt < 2; ++rt) {
#pragma unroll
        for (int r = 0; r < 16; ++r) {
            int h = 32 * rt + (r & 3) + 8 * (r >> 2) + 4 * hi;
            vb[h * 136 + 32 * w + c31] = (short)bfbits(cv[rt][r]);
        }
    }
    __syncthreads();
    {
        int row = tid >> 1, seg = tid & 1;
        const short8* cp = (const short8*)&cb[row * 136 + seg * 64];
        unsigned short* dst = (seg == 0 ? qo : ko) + (t0 + row) * 64;
#pragma unroll
        for (int i = 0; i < 8; ++i) ((short8*)dst)[i] = cp[i];
    }
#pragma unroll
    for (int i = 0; i < 4; ++i) {
        int slot = tid + 256 * i;
        int h = slot >> 4, tc = slot & 15;
        short8 vv = *(const short8*)&vb[h * 136 + 8 * tc];
        *(short8*)(vto + ((long)b * 64 + h) * 4096 + tl0 + 8 * tc) = vv;
    }
}

// ---------------- Kernel 2: MFMA flash attention (R11 shell, runtime chunk CT=1<<sh) ----------------
// 256 thr = 4 waves x 32 q-rows, 3-buffer counted-vmcnt pipeline. Chunk size is
// a runtime power-of-2 (16 fallback == R11-exact; 8 when ws_size permits ->
// grid 1152, more concurrent blocks/CU).
__global__ __launch_bounds__(256, 3) void attn_mfma(
    const unsigned short* __restrict__ qg,
    const unsigned short* __restrict__ kg,
    const unsigned short* __restrict__ vtg,
    unsigned short* __restrict__ Opart,
    float2* __restrict__ ml,
    float* __restrict__ outg,
    int sh, int CPB)
{
    __shared__ short kls[3][4096];
    __shared__ short vls[3][4096];

    const int CT = 1 << sh;
    const int tid = threadIdx.x;
    const int l = tid & 63, w = tid >> 6;     // w in {0..3}
    const int q = l & 31, hi = l >> 5;
    const int qs7 = q & 7;

    const int bid = blockIdx.x;
    const int b = bid & 7;
    const int j = bid >> 3;
    int qt = 0, ci = 0;
    {
        int acc = 0;
        for (int qq = 31; qq >= 0; --qq) {       // descending size (LPT)
            int nc = (2 * qq + 1 + CT) >> sh;    // ceil((2qq+2)/CT)
            if (j < acc + nc) { qt = qq; ci = j - acc; break; }
            acc += nc;
        }
    }
    const int nch = (2 * qt + 1 + CT) >> sh;
    int ntile = 2 * qt + 2 - CT * ci;
    if (ntile > CT) ntile = CT;
    const int c0 = (ci * CT) << 6;

    const int q0w = qt * 128 + 32 * w;
    const int qr = q0w + q;
    const int lastg = (q0w + 31) >> 6;         // wave's diagonal KV tile (global idx)

    const unsigned short* qb = qg + ((long)b * TT + qr) * HD;
    short8 qf[4];
#pragma unroll
    for (int ki = 0; ki < 4; ++ki) qf[ki] = *(const short8*)(qb + 16 * ki + 8 * hi);

    int ofs[2][4];
#pragma unroll
    for (int a = 0; a < 2; ++a)
#pragma unroll
        for (int i2 = 0; i2 < 4; ++i2)
            ofs[a][i2] = (32 * a + q) * 128 + 16 * ((2 * i2 + hi) ^ qs7);

    f32x16 oacc[2] = {};
    float m = -INFINITY, lsum = 0.f;           // lsum: own-half partial

    const unsigned short* kbase = kg + (long)b * TT * HD;
    const unsigned short* vbase = vtg + (long)b * HD * TT;

    const int r8 = l >> 3;
    const int blsw = (l & 7) ^ r8;
    const long koff0 = (long)(8 * w + r8) * HD + 8 * blsw;
    const long voff0 = (long)(8 * w + r8) * TT + 8 * blsw;

#define STAGE(buf_, s_) do {                                                            \
    _Pragma("unroll")                                                                   \
    for (int c_ = 0; c_ < 2; ++c_) {                                                    \
        const unsigned short* kp_ = kbase + (long)(s_) * HD + koff0 + (long)c_ * 32 * HD; \
        const unsigned short* vp_ = vbase + (s_) + voff0 + (long)c_ * 32 * TT;          \
        short* kd_ = &kls[buf_][2048 * c_ + 512 * w];                                   \
        short* vd_ = &vls[buf_][2048 * c_ + 512 * w];                                   \
        __builtin_amdgcn_global_load_lds((const __attribute__((address_space(1))) void*)kp_, \
                                         (__attribute__((address_space(3))) void*)kd_, 16, 0, 0); \
        __builtin_amdgcn_global_load_lds((const __attribute__((address_space(1))) void*)vp_, \
                                         (__attribute__((address_space(3))) void*)vd_, 16, 0, 0); \
    }                                                                                   \
} while (0)

    STAGE(0, c0);
    if (ntile > 1) STAGE(1, c0 + 64);

    int cur = 0, nxt2 = 2;
    for (int it = 0; it < ntile; ++it) {
        const int s0 = c0 + (it << 6);
        if (it + 1 < ntile) asm volatile("s_waitcnt vmcnt(4)" ::: "memory");
        else                asm volatile("s_waitcnt vmcnt(0)" ::: "memory");
        __builtin_amdgcn_s_barrier();
        __builtin_amdgcn_sched_barrier(0);
        if (it + 2 < ntile) STAGE(nxt2, s0 + 128);

        if (s0 <= q0w + 31) {
            const int gti = ci * CT + it;
            const int nkt = (gti == lastg && (w & 1) == 0) ? 1 : 2;
            const short* kb_ = kls[cur];
            const short* vb_ = vls[cur];

            // ---- S^T = K Q^T ----
            f32x16 sacc[2] = {};
            __builtin_amdgcn_s_setprio(1);
#pragma unroll
            for (int kt = 0; kt < 2; ++kt) {
                if (kt < nkt) {
#pragma unroll
                    for (int ki = 0; ki < 4; ++ki) {
                        short8 kf = *(const short8*)((const char*)kb_ + ofs[kt][ki]);
                        sacc[kt] = __builtin_amdgcn_mfma_f32_32x32x16_bf16(kf, qf[ki], sacc[kt], 0, 0, 0);
                    }
                }
            }
            __builtin_amdgcn_s_setprio(0);

            // ---- causal mask (diag tile only) ----
            if (gti == lastg) {
#pragma unroll
                for (int kt = 0; kt < 2; ++kt) {
                    if (kt >= nkt) continue;
#pragma unroll
                    for (int r = 0; r < 16; ++r) {
                        int kkg = s0 + 32 * kt + (r & 3) + 8 * (r >> 2) + 4 * hi;
                        if (kkg > qr) sacc[kt][r] = -INFINITY;
                    }
                }
            }

            // ---- lane-local tree max; rescale only beyond threshold (T13) ----
            float t8[8];
#pragma unroll
            for (int r = 0; r < 8; ++r) {
                float a = fmaxf(sacc[0][r], sacc[0][r + 8]);
                if (nkt == 2) a = fmaxf(a, fmaxf(sacc[1][r], sacc[1][r + 8]));
                t8[r] = a;
            }
            float pmax = fmaxf(fmaxf(fmaxf(t8[0], t8[1]), fmaxf(t8[2], t8[3])),
                               fmaxf(fmaxf(t8[4], t8[5]), fmaxf(t8[6], t8[7])));
            if (__any(pmax > m + 11.0f)) {     // rare in steady state
                pmax = fmaxf(pmax, __shfl_xor(pmax, 32, 64));
                float mn = fmaxf(m, pmax);
                float fac = fexp2(m - mn);
                lsum *= fac;
                oacc[0] *= fac;
                oacc[1] *= fac;
                m = mn;
            }

            // ---- P = exp2(S - m) via raw v_exp; pack via v_cvt_pk ----
            float rsum = 0.f;
            unsigned ulo[8], uhi[8];
#pragma unroll
            for (int kt = 0; kt < 2; ++kt) {
#pragma unroll
                for (int jj = 0; jj < 4; ++jj) {
                    if (kt < nkt) {
                        float p0 = fexp2(sacc[kt][4 * jj + 0] - m);
                        float p1 = fexp2(sacc[kt][4 * jj + 1] - m);
                        float p2 = fexp2(sacc[kt][4 * jj + 2] - m);
                        float p3 = fexp2(sacc[kt][4 * jj + 3] - m);
                        rsum += (p0 + p1) + (p2 + p3);
                        ulo[4 * kt + jj] = pack_bf2(p0, p1);
                        uhi[4 * kt + jj] = pack_bf2(p2, p3);
                    } else {
                        ulo[4 * kt + jj] = 0;
                        uhi[4 * kt + jj] = 0;
                    }
                }
            }
            lsum += rsum;                      // per-half; combined in epilogue

            // ---- O^T += V^T P (P -> A-frag via permlane32_swap, distinct ops) ----
            const int nks = 2 * nkt;
#pragma unroll
            for (int ks = 0; ks < 4; ++ks) {
                if (ks >= nks) continue;
                uint2v rlo = __builtin_amdgcn_permlane32_swap(ulo[2 * ks], ulo[2 * ks + 1], false, false);
                uint2v rhi = __builtin_amdgcn_permlane32_swap(uhi[2 * ks], uhi[2 * ks + 1], false, false);
                uint4v paw;
                paw[0] = rlo[0]; paw[1] = rhi[0]; paw[2] = rlo[1]; paw[3] = rhi[1];
                short8 pa = __builtin_bit_cast(short8, paw);
                __builtin_amdgcn_s_setprio(1);
#pragma unroll
                for (int dt = 0; dt < 2; ++dt) {
                    short8 vf = *(const short8*)((const char*)vb_ + ofs[dt][ks]);
                    oacc[dt] = __builtin_amdgcn_mfma_f32_32x32x16_bf16(vf, pa, oacc[dt], 0, 0, 0);
                }
                __builtin_amdgcn_s_setprio(0);
            }
        }
        cur = (cur == 2) ? 0 : cur + 1;
        nxt2 = (nxt2 == 2) ? 0 : nxt2 + 1;
    }
#undef STAGE

    lsum += __shfl_xor(lsum, 32, 64);          // combine per-half sums once

    const int lr = 32 * w + q;
    if (nch == 1) {
        const float inv = 1.f / lsum;
        float* op = outg + ((long)b * TT + qr) * HD;
#pragma unroll
        for (int dt = 0; dt < 2; ++dt) {
#pragma unroll
            for (int jj = 0; jj < 4; ++jj) {
                f32x4 o4;
                o4[0] = oacc[dt][4 * jj + 0] * inv;
                o4[1] = oacc[dt][4 * jj + 1] * inv;
                o4[2] = oacc[dt][4 * jj + 2] * inv;
                o4[3] = oacc[dt][4 * jj + 3] * inv;
                *(f32x4*)(op + 32 * dt + 8 * jj + 4 * hi) = o4;
            }
        }
    } else {
        const float inv = lsum > 0.f ? 1.f / lsum : 0.f;
        unsigned short* po = Opart + ((long)(b * CPB + j) * 128 + lr) * 64;
#pragma unroll
        for (int dt = 0; dt < 2; ++dt) {
#pragma unroll
            for (int jj = 0; jj < 4; ++jj) {
                uint2v u;
                u[0] = pack_bf2(oacc[dt][4 * jj + 0] * inv, oacc[dt][4 * jj + 1] * inv);
                u[1] = pack_bf2(oacc[dt][4 * jj + 2] * inv, oacc[dt][4 * jj + 3] * inv);
                *(uint2v*)(po + 32 * dt + 8 * jj + 4 * hi) = u;
            }
        }
        ml[(long)(b * CPB + j) * 128 + lr] = make_float2(m, lsum);
    }
}

// ---------------- Kernel 3: combine partials (runtime chunking; exp2 domain) ----------------
__global__ __launch_bounds__(256) void combine(
    const unsigned short* __restrict__ Opart,
    const float2* __restrict__ ml,
    float* __restrict__ outg,
    int sh, int qtmin, int CPB)
{
    const int CT = 1 << sh;
    const int bid = blockIdx.x;
    const int b = bid & 7, qt = qtmin + (bid >> 3);
    const int nc = (2 * qt + 1 + CT) >> sh;    // 2..8
    int jb = 0;
    for (int qq = 31; qq > qt; --qq) jb += (2 * qq + 1 + CT) >> sh;

    const int tid = threadIdx.x;
    const int row = tid >> 1, dh = (tid & 1) * 32;
    const long base = (long)(b * CPB + jb) * 128 + row;

    float mv[8], lv[8], M = -INFINITY;
#pragma unroll
    for (int c = 0; c < 8; ++c) {
        mv[c] = -INFINITY; lv[c] = 0.f;
        if (c < nc) {
            float2 t = ml[base + (long)c * 128];
            mv[c] = t.x; lv[c] = t.y;
            M = fmaxf(M, mv[c]);
        }
    }
    float L = 0.f, wt[8];
#pragma unroll
    for (int c = 0; c < 8; ++c) {
        wt[c] = (c < nc) ? lv[c] * fexp2(mv[c] - M) : 0.f;
        L += wt[c];
    }
    float acc[32];
#pragma unroll
    for (int i = 0; i < 32; ++i) acc[i] = 0.f;
#pragma unroll
    for (int c = 0; c < 8; ++c) {
        if (c < nc && wt[c] > 0.f) {
            const short8* op = (const short8*)(Opart + (base + (long)c * 128) * 64 + dh);
#pragma unroll
            for (int i = 0; i < 4; ++i) {
                short8 v = op[i];
#pragma unroll
                for (int e = 0; e < 8; ++e)
                    acc[8 * i + e] += wt[c] * bf2f((unsigned short)v[e]);
            }
        }
    }
    const float invL = 1.f / L;
    float* dst = outg + ((long)b * TT + qt * 128 + row) * HD + dh;
#pragma unroll
    for (int i = 0; i < 8; ++i) {
        f32x4 o;
        o[0] = acc[4 * i + 0] * invL; o[1] = acc[4 * i + 1] * invL;
        o[2] = acc[4 * i + 2] * invL; o[3] = acc[4 * i + 3] * invL;
        *(f32x4*)(dst + 4 * i) = o;
    }
}

extern "C" void kernel_launch(void* const* d_in, const int* in_sizes, int n_in,
                              void* d_out, int out_size, void* d_ws, size_t ws_size,
                              hipStream_t stream) {
    const float* x  = (const float*)d_in[0];
    const float* Wk = (const float*)d_in[1];
    const float* Wq = (const float*)d_in[2];
    const float* Wv = (const float*)d_in[3];
    float* out = (float*)d_out;

    const long N = (long)BB * TT * HD;                  // 2,097,152 elems / tensor
    unsigned short* q16 = (unsigned short*)d_ws;        // 4 MiB
    unsigned short* k16 = q16 + N;                      // 4 MiB
    unsigned short* vt16 = k16 + N;                     // 4 MiB (V^T [b][d][t])
    const size_t qkv_bytes = 12582912;

    // chunk-size selection: CT=8 (more blocks) iff partials fit the workspace
    // CT=8: CPB = sum_{qt} ceil((2qt+2)/8) = 144; need 12.58M + 18.87M + 1.18M
    int sh, CPB;
    {
        const size_t need8 = qkv_bytes + (size_t)144 * 8 * 128 * 64 * 2
                                       + (size_t)144 * 8 * 128 * 8;   // 32,636,928
        if (ws_size >= need8) { sh = 3; CPB = 144; }
        else                  { sh = 4; CPB = 80;  }    // byte-identical to R11 layout
    }
    const int CT = 1 << sh;
    unsigned short* Opart = (unsigned short*)((char*)d_ws + qkv_bytes);
    float2* mlp = (float2*)((char*)d_ws + qkv_bytes + (size_t)CPB * 8 * 128 * 64 * 2);
    const int qtmin = CT >> 1;                          // first qt needing combine

    qkv_proj_mfma<<<BB * TT / 128, 256, 0, stream>>>(x, Wk, Wq, Wv, q16, k16, vt16);
    attn_mfma<<<8 * CPB, 256, 0, stream>>>(q16, k16, vt16, Opart, mlp, out, sh, CPB);
    combine<<<8 * (32 - qtmin), 256, 0, stream>>>(Opart, mlp, out, sh, qtmin, CPB);
}